// Round 7
// baseline (279.616 us; speedup 1.0000x reference)
//
#include <hip/hip_runtime.h>

#define CLS_LO 1.0e-4f
#define CLS_HI 0.9999f   // float(1.0 - 0.0001)

// ws layout (floats):
//   [0, B*5*M)           per-image segment arrays: counts[M] | sums[3M] | sumsq[M]  (memset 0)
//   [B*5*M]              done-counter (uint, memset 0) + 3 pad
//   [B*5*M+4, +3*B*NBx)  per-block partial slots {cls, reg, np}  (no init needed)

__device__ __forceinline__ float smooth_l1(float d) {
    d = fabsf(d);
    return (d <= (1.0f / 9.0f)) ? (4.5f * d * d) : (d - (0.5f / 9.0f));
}

__device__ __forceinline__ float aload(const float* p) {
    return __hip_atomic_load(p, __ATOMIC_RELAXED, __HIP_MEMORY_SCOPE_AGENT);
}
__device__ __forceinline__ void astore(float* p, float v) {
    __hip_atomic_store(p, v, __ATOMIC_RELAXED, __HIP_MEMORY_SCOPE_AGENT);
}

template <int CPA4>
__global__ void __launch_bounds__(256)
det_fused_kernel(const float* __restrict__ cls,
                 const float* __restrict__ reg,
                 const float* __restrict__ anc,
                 const float* __restrict__ ann,
                 float* __restrict__ ws,
                 float* __restrict__ out,
                 int A, int C, int M, int B, int NBx)
{
    const int gid = blockIdx.x;
    const int b   = gid / NBx;
    const int bx  = gid - b * NBx;
    const int tid = threadIdx.x;
    const int a0  = bx * 256;
    const int a   = a0 + tid;
    const int cpa4 = CPA4 ? CPA4 : (C >> 2);

    unsigned int* done = (unsigned int*)(ws + (size_t)B * 5 * M);
    float* slots = ws + (size_t)B * 5 * M + 4;

    __shared__ float4 sbox[64];             // box corners [x1,y1,x2,y2]
    __shared__ float  slbl[64];
    __shared__ float  s_cnt[64], s_sx[64], s_sy[64], s_sz[64], s_sq[64];
    __shared__ float  smask[256];
    __shared__ float  s_part[4][3];
    __shared__ bool   s_last;

    if (tid < M) {
        const float* bp = ann + ((size_t)b * M + tid) * 5;
        sbox[tid] = make_float4(bp[0], bp[1], bp[2], bp[3]);
        slbl[tid] = bp[4];
        s_cnt[tid] = 0.f; s_sx[tid] = 0.f; s_sy[tid] = 0.f; s_sz[tid] = 0.f; s_sq[tid] = 0.f;
    }
    smask[tid] = 0.f;
    __syncthreads();

    float contrib_cls = 0.f, contrib_reg = 0.f, contrib_np = 0.f;

    // ---------------- phase 1: IoU assignment + rare positive work ----------------
    if (a < A) {
        float4 av = ((const float4*)anc)[a];       // yx layout: [y1, x1, y2, x2]
        const float ay1 = av.x, ax1 = av.y, ay2 = av.z, ax2 = av.w;
        const float aw  = ax2 - ax1;
        const float ah  = ay2 - ay1;
        const float area_a = ah * aw;

        // division-free argmax over iou_j = inter_j/ua_j (compare inter*bD > bN*ua)
        float bN = -1.f, bD = 1.f;
        int   bj = 0;
#define IOU_BODY(j)                                                              \
        {                                                                        \
            const float4 bx4 = sbox[(j)];                                        \
            float iw = fminf(ax2, bx4.z) - fmaxf(ax1, bx4.x); iw = fmaxf(iw, 0.f);\
            float ih = fminf(ay2, bx4.w) - fmaxf(ay1, bx4.y); ih = fmaxf(ih, 0.f);\
            const float inter = iw * ih;                                         \
            const float ua = fmaxf(area_a + (bx4.z - bx4.x) * (bx4.w - bx4.y)    \
                                   - inter, 1e-8f);                              \
            if (inter * bD > bN * ua) { bN = inter; bD = ua; bj = (j); }         \
        }
        if (M == 32) {
            #pragma unroll
            for (int j = 0; j < 32; j++) IOU_BODY(j)
        } else {
            for (int j = 0; j < M; j++) IOU_BODY(j)
        }
#undef IOU_BODY
        const bool pos = (2.f * bN >= bD);         // iou >= 0.5
        const bool neg = (bN < 0.4f * bD);         // iou < 0.4
        smask[tid] = (pos || neg) ? 1.f : 0.f;

        if (pos) {
            contrib_np = 1.0f;

            // focal fixup at assigned class: phase 2 adds the uniform negative
            // term for every class; swap in the positive term at L.
            const float* cbase = cls + ((size_t)b * A + a) * (size_t)C;
            const int L = (int)slbl[bj];
            const float p = fminf(fmaxf(cbase[L], CLS_LO), CLS_HI);
            contrib_cls = 0.25f * (1.f - p) * (1.f - p) * (-__logf(p))
                        - 0.75f * p * p * (-__logf(1.f - p));

            const float* rp = reg + ((size_t)b * A + a) * 7;
            const float r0 = rp[0], r1 = rp[1], r2 = rp[2], r3 = rp[3];
            const float e0 = rp[4], e1 = rp[5], e2 = rp[6];

            const float4 bx4 = sbox[bj];
            float gw = bx4.z - bx4.x;
            float gh = bx4.w - bx4.y;
            const float gcx = bx4.x + 0.5f * gw;
            const float gcy = bx4.y + 0.5f * gh;
            gw = fmaxf(gw, 1.f);
            gh = fmaxf(gh, 1.f);
            const float acx = ax1 + 0.5f * aw;
            const float acy = ay1 + 0.5f * ah;
            contrib_reg = smooth_l1((gcy - acy) / ah - r0) +
                          smooth_l1((gcx - acx) / aw - r1) +
                          smooth_l1(__logf(gh / ah) - r2) +
                          smooth_l1(__logf(gw / aw) - r3);

            atomicAdd(&s_cnt[bj], 1.f);
            atomicAdd(&s_sx[bj], e0);
            atomicAdd(&s_sy[bj], e1);
            atomicAdd(&s_sz[bj], e2);
            atomicAdd(&s_sq[bj], e0 * e0 + e1 * e1 + e2 * e2);
        }
    }
    __syncthreads();

    // ---------------- phase 2: coalesced masked focal sweep over block tile ----------------
    {
        const int nA = min(256, A - a0);
        const float4* tile = (const float4*)(cls + ((size_t)b * A + a0) * (size_t)C);
        float acc = 0.f;                      // sum of m * p^2 * log(1-p); scaled at end

        if (CPA4 == 20 && nA == 256) {
            // 256 anchors x 20 float4 = 5120 float4s; 4 groups of 5 batched loads
            #pragma unroll
            for (int g = 0; g < 4; g++) {
                float4 v[5];
                float  mk[5];
                #pragma unroll
                for (int k = 0; k < 5; k++)
                    v[k] = tile[tid + 256 * (g * 5 + k)];
                #pragma unroll
                for (int k = 0; k < 5; k++)
                    mk[k] = smask[(((unsigned)tid + 256u * (g * 5 + k)) * 52429u) >> 20]; // /20 exact
                #pragma unroll
                for (int k = 0; k < 5; k++) {
                    float p, l, s = 0.f;
                    p = fminf(fmaxf(v[k].x, CLS_LO), CLS_HI); l = __logf(1.f - p); s = fmaf(p * p, l, s);
                    p = fminf(fmaxf(v[k].y, CLS_LO), CLS_HI); l = __logf(1.f - p); s = fmaf(p * p, l, s);
                    p = fminf(fmaxf(v[k].z, CLS_LO), CLS_HI); l = __logf(1.f - p); s = fmaf(p * p, l, s);
                    p = fminf(fmaxf(v[k].w, CLS_LO), CLS_HI); l = __logf(1.f - p); s = fmaf(p * p, l, s);
                    acc = fmaf(mk[k], s, acc);
                }
            }
        } else if (nA > 0) {
            const int n4 = nA * cpa4;
            for (int idx = tid; idx < n4; idx += 256) {
                const float m = smask[(unsigned)idx / (unsigned)cpa4];
                const float4 vv = tile[idx];
                float p, l, s = 0.f;
                p = fminf(fmaxf(vv.x, CLS_LO), CLS_HI); l = __logf(1.f - p); s = fmaf(p * p, l, s);
                p = fminf(fmaxf(vv.y, CLS_LO), CLS_HI); l = __logf(1.f - p); s = fmaf(p * p, l, s);
                p = fminf(fmaxf(vv.z, CLS_LO), CLS_HI); l = __logf(1.f - p); s = fmaf(p * p, l, s);
                p = fminf(fmaxf(vv.w, CLS_LO), CLS_HI); l = __logf(1.f - p); s = fmaf(p * p, l, s);
                acc = fmaf(m, s, acc);
            }
        }
        contrib_cls -= 0.75f * acc;           // neg focal = 0.75 * p^2 * (-log(1-p))
    }

    // ---------------- block reduction + global flush ----------------
    for (int off = 32; off > 0; off >>= 1) {
        contrib_cls += __shfl_down(contrib_cls, off, 64);
        contrib_reg += __shfl_down(contrib_reg, off, 64);
        contrib_np  += __shfl_down(contrib_np,  off, 64);
    }
    if ((tid & 63) == 0) {
        s_part[tid >> 6][0] = contrib_cls;
        s_part[tid >> 6][1] = contrib_reg;
        s_part[tid >> 6][2] = contrib_np;
    }
    __syncthreads();

    float* wsb = ws + (size_t)b * 5 * M;
    if (tid < M) {
        const float c = s_cnt[tid];
        if (c != 0.f) {   // only blocks containing positive anchors fire global atomics
            atomicAdd(&wsb[tid], c);
            atomicAdd(&wsb[M + 3 * tid + 0], s_sx[tid]);
            atomicAdd(&wsb[M + 3 * tid + 1], s_sy[tid]);
            atomicAdd(&wsb[M + 3 * tid + 2], s_sz[tid]);
            atomicAdd(&wsb[4 * M + tid], s_sq[tid]);
        }
    }
    if (tid == 0) {
        float* slot = slots + 3 * (size_t)gid;
        astore(&slot[0], s_part[0][0] + s_part[1][0] + s_part[2][0] + s_part[3][0]);
        astore(&slot[1], s_part[0][1] + s_part[1][1] + s_part[2][1] + s_part[3][1]);
        astore(&slot[2], s_part[0][2] + s_part[1][2] + s_part[2][2] + s_part[3][2]);
        __threadfence();
        const unsigned old = atomicAdd(done, 1u);
        s_last = (old == (unsigned)(B * NBx - 1));
    }
    __syncthreads();
    if (!s_last) return;

    // ---------------- final phase (last block only) ----------------
    __threadfence();
    __shared__ float s_scal[8][3];
    __shared__ float s_emb[8];
    __shared__ float tmp[4][3];
    if (tid < B) s_emb[tid] = 0.f;

    for (int bb = 0; bb < B; bb++) {
        float c = 0.f, r = 0.f, n = 0.f;
        for (int i = tid; i < NBx; i += 256) {
            const float* slot = slots + 3 * (size_t)(bb * NBx + i);
            c += aload(&slot[0]);
            r += aload(&slot[1]);
            n += aload(&slot[2]);
        }
        for (int off = 32; off > 0; off >>= 1) {
            c += __shfl_down(c, off, 64);
            r += __shfl_down(r, off, 64);
            n += __shfl_down(n, off, 64);
        }
        if ((tid & 63) == 0) { tmp[tid >> 6][0] = c; tmp[tid >> 6][1] = r; tmp[tid >> 6][2] = n; }
        __syncthreads();
        if (tid == 0) {
            s_scal[bb][0] = tmp[0][0] + tmp[1][0] + tmp[2][0] + tmp[3][0];
            s_scal[bb][1] = tmp[0][1] + tmp[1][1] + tmp[2][1] + tmp[3][1];
            s_scal[bb][2] = tmp[0][2] + tmp[1][2] + tmp[2][2] + tmp[3][2];
        }
        __syncthreads();
    }

    if (tid < B * M) {
        const int bb = tid / M;
        const int m  = tid - bb * M;
        const float* sg = ws + (size_t)bb * 5 * M;
        const float c = aload(&sg[m]);
        float mx = 0.f, my = 0.f, mz = 0.f, pa = 0.f;
        if (c > 0.f) {
            mx = aload(&sg[M + 3 * m + 0]) / c;
            my = aload(&sg[M + 3 * m + 1]) / c;
            mz = aload(&sg[M + 3 * m + 2]) / c;
            // sum |e - mean|^2 = sum|e|^2 - c*|mean|^2
            const float sq = aload(&sg[4 * M + m]) - c * (mx * mx + my * my + mz * mz);
            pa = sq / fmaxf(c * 3.f, 1.f);
        }
        out[3 + (size_t)(bb * M + m) * 3 + 0] = mx;
        out[3 + (size_t)(bb * M + m) * 3 + 1] = my;
        out[3 + (size_t)(bb * M + m) * 3 + 2] = mz;
        atomicAdd(&s_emb[bb], pa);
    }
    __syncthreads();

    if (tid == 0) {
        float cl = 0.f, rl = 0.f, el = 0.f;
        for (int bb = 0; bb < B; bb++) {
            const float np = s_scal[bb][2];
            cl += s_scal[bb][0] / fmaxf(np, 1.f);
            rl += s_scal[bb][1] / fmaxf(4.f * np, 1.f);
            el += s_emb[bb] / (float)M;
        }
        const float invB = 1.f / (float)B;
        out[0] = cl * invB;
        out[1] = rl * invB * 50.f;
        out[2] = el * invB;
    }
}

extern "C" void kernel_launch(void* const* d_in, const int* in_sizes, int n_in,
                              void* d_out, int out_size, void* d_ws, size_t ws_size,
                              hipStream_t stream) {
    const float* cls = (const float*)d_in[0];
    const float* reg = (const float*)d_in[1];
    const float* anc = (const float*)d_in[2];
    const float* ann = (const float*)d_in[3];
    float* out = (float*)d_out;
    float* ws  = (float*)d_ws;

    const int A = in_sizes[2] / 4;               // anchors: (1, A, 4)
    const int B = in_sizes[1] / (A * 7);         // regressions: (B, A, 7)
    const int C = in_sizes[0] / (B * A);         // classifications: (B, A, C)
    const int M = in_sizes[3] / (B * 5);         // annotations: (B, M, 5)
    const int NBx = (A + 255) / 256;

    // zero segment arrays + done-counter only (slots are written unconditionally)
    hipMemsetAsync(ws, 0, ((size_t)B * 5 * M + 4) * sizeof(float), stream);

    dim3 grid(B * NBx);
    if (C == 80)
        det_fused_kernel<20><<<grid, 256, 0, stream>>>(cls, reg, anc, ann, ws, out, A, C, M, B, NBx);
    else
        det_fused_kernel<0><<<grid, 256, 0, stream>>>(cls, reg, anc, ann, ws, out, A, C, M, B, NBx);
}

// Round 8
// 252.046 us; speedup vs baseline: 1.1094x; 1.1094x over previous
//
#include <hip/hip_runtime.h>

#define CLS_LO 1.0e-4f
#define CLS_HI 0.9999f   // float(1.0 - 0.0001)

// ws layout (floats), per image b with stride S = 5*M + 3*64:
//   [0,M) counts | [M,4M) sums3 | [4M,5M) sumsq | [5M,5M+192) partials {cls,reg,np} x 64 slots
// cls_loss is computed as: (unmasked neg-focal sum over ALL anchors)  [focal kernel]
//   + per-anchor corrections for pos (swap class-L term) and ignored (subtract row) [assign kernel]

__device__ __forceinline__ float smooth_l1(float d) {
    d = fabsf(d);
    return (d <= (1.0f / 9.0f)) ? (4.5f * d * d) : (d - (0.5f / 9.0f));
}

// ---------------- kernel A: IoU assignment + pos/ignored corrections ----------------
template <int CPA4>   // 20 when C==80, else 0 (generic)
__global__ void __launch_bounds__(256, 4)
det_assign_kernel(const float* __restrict__ cls,
                  const float* __restrict__ reg,
                  const float* __restrict__ anc,
                  const float* __restrict__ ann,
                  float* __restrict__ ws,
                  int A, int C, int M)
{
    const int b   = blockIdx.y;
    const int tid = threadIdx.x;
    const int a   = blockIdx.x * 256 + tid;
    const int S   = 5 * M + 192;

    __shared__ float4 sbox[64];             // box corners [x1,y1,x2,y2]
    __shared__ float  slbl[64];
    __shared__ float  s_cnt[64], s_sx[64], s_sy[64], s_sz[64], s_sq[64];
    __shared__ float  s_part[4][3];

    if (tid < M) {
        const float* bp = ann + ((size_t)b * M + tid) * 5;
        sbox[tid] = make_float4(bp[0], bp[1], bp[2], bp[3]);
        slbl[tid] = bp[4];
        s_cnt[tid] = 0.f; s_sx[tid] = 0.f; s_sy[tid] = 0.f; s_sz[tid] = 0.f; s_sq[tid] = 0.f;
    }
    __syncthreads();

    float contrib_cls = 0.f, contrib_reg = 0.f, contrib_np = 0.f;

    if (a < A) {
        float4 av = ((const float4*)anc)[a];       // yx layout: [y1, x1, y2, x2]
        const float ay1 = av.x, ax1 = av.y, ay2 = av.z, ax2 = av.w;
        const float aw  = ax2 - ax1;
        const float ah  = ay2 - ay1;
        const float area_a = ah * aw;

        // division-free argmax over iou_j = inter_j/ua_j (compare inter*bD > bN*ua)
        float bN = -1.f, bD = 1.f;
        int   bj = 0;
#define IOU_BODY(j)                                                               \
        {                                                                         \
            const float4 bx4 = sbox[(j)];                                         \
            float iw = fminf(ax2, bx4.z) - fmaxf(ax1, bx4.x); iw = fmaxf(iw, 0.f);\
            float ih = fminf(ay2, bx4.w) - fmaxf(ay1, bx4.y); ih = fmaxf(ih, 0.f);\
            const float inter = iw * ih;                                          \
            const float ua = fmaxf(area_a + (bx4.z - bx4.x) * (bx4.w - bx4.y)     \
                                   - inter, 1e-8f);                               \
            if (inter * bD > bN * ua) { bN = inter; bD = ua; bj = (j); }          \
        }
        if (M == 32) {
            #pragma unroll
            for (int j = 0; j < 32; j++) IOU_BODY(j)
        } else {
            for (int j = 0; j < M; j++) IOU_BODY(j)
        }
#undef IOU_BODY
        const bool pos = (2.f * bN >= bD);         // iou >= 0.5
        const bool neg = (bN < 0.4f * bD);         // iou < 0.4

        if (pos) {
            contrib_np = 1.0f;

            // swap the class-L term: remove uniform negative term, add positive term
            const float* cbase = cls + ((size_t)b * A + a) * (size_t)C;
            const int L = (int)slbl[bj];
            const float p = fminf(fmaxf(cbase[L], CLS_LO), CLS_HI);
            contrib_cls = 0.25f * (1.f - p) * (1.f - p) * (-__logf(p))
                        - 0.75f * p * p * (-__logf(1.f - p));

            const float* rp = reg + ((size_t)b * A + a) * 7;
            const float r0 = rp[0], r1 = rp[1], r2 = rp[2], r3 = rp[3];
            const float e0 = rp[4], e1 = rp[5], e2 = rp[6];

            const float4 bx4 = sbox[bj];
            float gw = bx4.z - bx4.x;
            float gh = bx4.w - bx4.y;
            const float gcx = bx4.x + 0.5f * gw;
            const float gcy = bx4.y + 0.5f * gh;
            gw = fmaxf(gw, 1.f);
            gh = fmaxf(gh, 1.f);
            const float acx = ax1 + 0.5f * aw;
            const float acy = ay1 + 0.5f * ah;
            contrib_reg = smooth_l1((gcy - acy) / ah - r0) +
                          smooth_l1((gcx - acx) / aw - r1) +
                          smooth_l1(__logf(gh / ah) - r2) +
                          smooth_l1(__logf(gw / aw) - r3);

            atomicAdd(&s_cnt[bj], 1.f);
            atomicAdd(&s_sx[bj], e0);
            atomicAdd(&s_sy[bj], e1);
            atomicAdd(&s_sz[bj], e2);
            atomicAdd(&s_sq[bj], e0 * e0 + e1 * e1 + e2 * e2);
        } else if (!neg) {
            // IGNORED anchor (0.4 <= iou < 0.5): subtract its whole row's neg-focal
            // sum (the focal kernel adds it unconditionally). Rare (~few %).
            const float* rowp = cls + ((size_t)b * A + a) * (size_t)C;
            float s = 0.f;                    // sum of p^2 * log(1-p)  (negative)
            if (CPA4 == 20) {
                const float4* r4 = (const float4*)rowp;
                #pragma unroll 5
                for (int k = 0; k < 20; k++) {
                    const float4 v = r4[k];
                    float p;
                    p = fminf(fmaxf(v.x, CLS_LO), CLS_HI); s = fmaf(p * p, __logf(1.f - p), s);
                    p = fminf(fmaxf(v.y, CLS_LO), CLS_HI); s = fmaf(p * p, __logf(1.f - p), s);
                    p = fminf(fmaxf(v.z, CLS_LO), CLS_HI); s = fmaf(p * p, __logf(1.f - p), s);
                    p = fminf(fmaxf(v.w, CLS_LO), CLS_HI); s = fmaf(p * p, __logf(1.f - p), s);
                }
            } else {
                for (int c = 0; c < C; c++) {
                    const float p = fminf(fmaxf(rowp[c], CLS_LO), CLS_HI);
                    s = fmaf(p * p, __logf(1.f - p), s);
                }
            }
            contrib_cls = 0.75f * s;          // negative: removes row from unmasked total
        }
    }

    for (int off = 32; off > 0; off >>= 1) {
        contrib_cls += __shfl_down(contrib_cls, off, 64);
        contrib_reg += __shfl_down(contrib_reg, off, 64);
        contrib_np  += __shfl_down(contrib_np,  off, 64);
    }
    if ((tid & 63) == 0) {
        s_part[tid >> 6][0] = contrib_cls;
        s_part[tid >> 6][1] = contrib_reg;
        s_part[tid >> 6][2] = contrib_np;
    }
    __syncthreads();

    float* wsb = ws + (size_t)b * S;
    if (tid < M) {
        const float c = s_cnt[tid];
        if (c != 0.f) {   // only blocks containing positive anchors fire global atomics
            atomicAdd(&wsb[tid], c);
            atomicAdd(&wsb[M + 3 * tid + 0], s_sx[tid]);
            atomicAdd(&wsb[M + 3 * tid + 1], s_sy[tid]);
            atomicAdd(&wsb[M + 3 * tid + 2], s_sz[tid]);
            atomicAdd(&wsb[4 * M + tid], s_sq[tid]);
        }
    }
    if (tid == 0) {
        const float c = s_part[0][0] + s_part[1][0] + s_part[2][0] + s_part[3][0];
        const float r = s_part[0][1] + s_part[1][1] + s_part[2][1] + s_part[3][1];
        const float n = s_part[0][2] + s_part[1][2] + s_part[2][2] + s_part[3][2];
        float* slot = wsb + 5 * M + 3 * (blockIdx.x & 63);
        if (c != 0.f) atomicAdd(&slot[0], c);
        if (r != 0.f) atomicAdd(&slot[1], r);
        if (n != 0.f) atomicAdd(&slot[2], n);
    }
}

// ---------------- kernel B: UNMASKED streaming focal reduction ----------------
// Pure flat reduce over one image's A*C floats. No LDS in the loop, no mask,
// no divergence: 8 independent float4 loads per thread, then compute.
template <bool FAST>
__global__ void __launch_bounds__(256, 4)
det_focal_kernel(const float* __restrict__ cls,
                 float* __restrict__ ws,
                 int A, int C, int M, int N4 /* per-image float4 count (FAST) */)
{
    const int b   = blockIdx.y;
    const int tid = threadIdx.x;
    const int S   = 5 * M + 192;
    float acc = 0.f;                          // sum of p^2 * log(1-p)   (negative)

    if (FAST) {
        const float4* img = (const float4*)(cls + (size_t)b * A * (size_t)C);
        const int base = blockIdx.x * 2048;
        if (base + 2048 <= N4) {
            float4 v[8];
            #pragma unroll
            for (int k = 0; k < 8; k++)
                v[k] = img[base + tid + 256 * k];     // 8 loads in flight
            #pragma unroll
            for (int k = 0; k < 8; k++) {
                float p;
                p = fminf(fmaxf(v[k].x, CLS_LO), CLS_HI); acc = fmaf(p * p, __logf(1.f - p), acc);
                p = fminf(fmaxf(v[k].y, CLS_LO), CLS_HI); acc = fmaf(p * p, __logf(1.f - p), acc);
                p = fminf(fmaxf(v[k].z, CLS_LO), CLS_HI); acc = fmaf(p * p, __logf(1.f - p), acc);
                p = fminf(fmaxf(v[k].w, CLS_LO), CLS_HI); acc = fmaf(p * p, __logf(1.f - p), acc);
            }
        } else {
            for (int idx = base + tid; idx < N4; idx += 256) {
                const float4 v = img[idx];
                float p;
                p = fminf(fmaxf(v.x, CLS_LO), CLS_HI); acc = fmaf(p * p, __logf(1.f - p), acc);
                p = fminf(fmaxf(v.y, CLS_LO), CLS_HI); acc = fmaf(p * p, __logf(1.f - p), acc);
                p = fminf(fmaxf(v.z, CLS_LO), CLS_HI); acc = fmaf(p * p, __logf(1.f - p), acc);
                p = fminf(fmaxf(v.w, CLS_LO), CLS_HI); acc = fmaf(p * p, __logf(1.f - p), acc);
            }
        }
    } else {
        const float* img = cls + (size_t)b * A * (size_t)C;
        const int n = A * C;
        const int stride = gridDim.x * 256;
        for (int i = blockIdx.x * 256 + tid; i < n; i += stride) {
            const float p = fminf(fmaxf(img[i], CLS_LO), CLS_HI);
            acc = fmaf(p * p, __logf(1.f - p), acc);
        }
    }

    for (int off = 32; off > 0; off >>= 1)
        acc += __shfl_down(acc, off, 64);
    __shared__ float sp[4];
    if ((tid & 63) == 0) sp[tid >> 6] = acc;
    __syncthreads();
    if (tid == 0) {
        const float tot = sp[0] + sp[1] + sp[2] + sp[3];
        // neg focal = 0.75 * p^2 * (-log(1-p)); tot is negative
        atomicAdd(&ws[(size_t)b * S + 5 * M + 3 * (blockIdx.x & 63) + 0], -0.75f * tot);
    }
}

// ---------------- final: combine partials, emit losses + embedding means ----------------
__global__ void __launch_bounds__(256)
det_final_kernel(const float* __restrict__ ws,
                 float* __restrict__ out,
                 int B, int M)
{
    const int t = threadIdx.x;
    const int S = 5 * M + 192;
    __shared__ float s_scal[8][3];
    __shared__ float s_emb[8];
    if (t < B) s_emb[t] = 0.f;

    // each 64-lane wave reduces one image's 64 partial slots
    const int k = t & 63;
    for (int b = t >> 6; b < B; b += 4) {
        const float* slot = ws + (size_t)b * S + 5 * M + 3 * k;
        float c = slot[0], r = slot[1], n = slot[2];
        for (int off = 32; off > 0; off >>= 1) {
            c += __shfl_down(c, off, 64);
            r += __shfl_down(r, off, 64);
            n += __shfl_down(n, off, 64);
        }
        if (k == 0) { s_scal[b][0] = c; s_scal[b][1] = r; s_scal[b][2] = n; }
    }
    __syncthreads();

    if (t < B * M) {
        const int b = t / M;
        const int m = t - b * M;
        const float* wsb = ws + (size_t)b * S;
        const float c = wsb[m];
        float mx = 0.f, my = 0.f, mz = 0.f, pa = 0.f;
        if (c > 0.f) {
            mx = wsb[M + 3 * m + 0] / c;
            my = wsb[M + 3 * m + 1] / c;
            mz = wsb[M + 3 * m + 2] / c;
            // sum |e - mean|^2 = sum|e|^2 - c*|mean|^2
            const float sq = wsb[4 * M + m] - c * (mx * mx + my * my + mz * mz);
            pa = sq / fmaxf(c * 3.f, 1.f);
        }
        out[3 + (size_t)(b * M + m) * 3 + 0] = mx;
        out[3 + (size_t)(b * M + m) * 3 + 1] = my;
        out[3 + (size_t)(b * M + m) * 3 + 2] = mz;
        atomicAdd(&s_emb[b], pa);
    }
    __syncthreads();

    if (t == 0) {
        float cl = 0.f, rl = 0.f, el = 0.f;
        for (int b = 0; b < B; b++) {
            const float np = s_scal[b][2];
            cl += s_scal[b][0] / fmaxf(np, 1.f);
            rl += s_scal[b][1] / fmaxf(4.f * np, 1.f);
            el += s_emb[b] / (float)M;
        }
        const float invB = 1.f / (float)B;
        out[0] = cl * invB;
        out[1] = rl * invB * 50.f;
        out[2] = el * invB;
    }
}

extern "C" void kernel_launch(void* const* d_in, const int* in_sizes, int n_in,
                              void* d_out, int out_size, void* d_ws, size_t ws_size,
                              hipStream_t stream) {
    const float* cls = (const float*)d_in[0];
    const float* reg = (const float*)d_in[1];
    const float* anc = (const float*)d_in[2];
    const float* ann = (const float*)d_in[3];
    float* out = (float*)d_out;
    float* ws  = (float*)d_ws;

    const int A = in_sizes[2] / 4;               // anchors: (1, A, 4)
    const int B = in_sizes[1] / (A * 7);         // regressions: (B, A, 7)
    const int C = in_sizes[0] / (B * A);         // classifications: (B, A, C)
    const int M = in_sizes[3] / (B * 5);         // annotations: (B, M, 5)
    const int S = 5 * M + 192;

    hipMemsetAsync(ws, 0, (size_t)B * S * sizeof(float), stream);

    dim3 gridA((A + 255) / 256, B);
    if (C == 80)
        det_assign_kernel<20><<<gridA, 256, 0, stream>>>(cls, reg, anc, ann, ws, A, C, M);
    else
        det_assign_kernel<0><<<gridA, 256, 0, stream>>>(cls, reg, anc, ann, ws, A, C, M);

    if ((C & 3) == 0) {
        const int N4 = A * (C >> 2);             // per-image float4 count
        dim3 gridF((N4 + 2047) / 2048, B);
        det_focal_kernel<true><<<gridF, 256, 0, stream>>>(cls, ws, A, C, M, N4);
    } else {
        const int n = A * C;
        dim3 gridF((n + 8191) / 8192, B);
        det_focal_kernel<false><<<gridF, 256, 0, stream>>>(cls, ws, A, C, M, 0);
    }

    det_final_kernel<<<1, 256, 0, stream>>>(ws, out, B, M);
}